// Round 2
// baseline (457.418 us; speedup 1.0000x reference)
//
#include <hip/hip_runtime.h>

#define BT   16
#define FIN  16
#define FOUT 32

// ---------------- CSR build ----------------

__global__ void hist_kernel(const int* __restrict__ rows, int* __restrict__ counts, int E) {
    int e = blockIdx.x * blockDim.x + threadIdx.x;
    if (e < E) atomicAdd(&counts[rows[e]], 1);
}

__global__ void scan_kernel(const int* __restrict__ counts, int* __restrict__ row_start, int N) {
    __shared__ int part[1024];
    int t = threadIdx.x;
    int per = (N + 1023) >> 10;
    int base = t * per;
    int s = 0;
#pragma unroll 4
    for (int i = 0; i < per; ++i) {
        int idx = base + i;
        if (idx < N) s += counts[idx];
    }
    part[t] = s;
    __syncthreads();
    for (int off = 1; off < 1024; off <<= 1) {
        int v = (t >= off) ? part[t - off] : 0;
        __syncthreads();
        part[t] += v;
        __syncthreads();
    }
    int run = (t == 0) ? 0 : part[t - 1];
#pragma unroll 4
    for (int i = 0; i < per; ++i) {
        int idx = base + i;
        if (idx < N) {
            row_start[idx] = run;
            run += counts[idx];
        }
    }
    if (t == 1023) row_start[N] = part[1023];
}

__global__ void scatter_kernel(const int* __restrict__ rows, const int* __restrict__ cols,
                               const float* __restrict__ vals,
                               const int* __restrict__ row_start, int* __restrict__ cursor,
                               int* __restrict__ col_s, float* __restrict__ val_s, int E) {
    int e = blockIdx.x * blockDim.x + threadIdx.x;
    if (e >= E) return;
    int r = rows[e];
    int pos = row_start[r] + atomicAdd(&cursor[r], 1);
    col_s[pos] = cols[e];
    val_s[pos] = vals[e];
}

// ---------------- gate[bt*N+n] = gate(static[bt,n,:]) ----------------

__global__ __launch_bounds__(256) void gate_kernel(
        const float* __restrict__ st,     // [BT, N, 8] flat
        const float* __restrict__ Wg1, const float* __restrict__ bg1,
        const float* __restrict__ Wg2, const float* __restrict__ bg2,
        const float* __restrict__ min_gate,
        float* __restrict__ gate, int total) {
    int t = blockIdx.x * blockDim.x + threadIdx.x;
    if (t >= total) return;
    const float4* sp = (const float4*)(st + (size_t)t * 8);
    float4 s0 = sp[0], s1 = sp[1];
    float g1 = s0.x * Wg1[0] + s0.y * Wg1[1] + s0.z * Wg1[2] + bg1[0];
    float g2 = s0.w * Wg2[0] + s1.x * Wg2[1] + s1.y * Wg2[2] + s1.z * Wg2[3] + s1.w * Wg2[4] + bg2[0];
    g1 = 1.f / (1.f + __expf(-g1));
    g2 = 1.f / (1.f + __expf(-g2));
    gate[t] = fmaxf(g1 * g2, min_gate[0]);
}

// ---------------- fused SpMM (direct water gather) + 16->32 matmul + LayerNorm ----------------

__global__ __launch_bounds__(256) void spmm_ln_kernel(
        const float* __restrict__ water,      // [BT, N, 16]
        const float* __restrict__ gate,       // [BT, N]
        const int* __restrict__ row_start,    // [N+1]
        const int* __restrict__ col_s,
        const float* __restrict__ val_s,
        const float* __restrict__ W,          // [16, 32]
        const float* __restrict__ bvec,       // [32]
        const float* __restrict__ gamma,
        const float* __restrict__ beta,
        float* __restrict__ out, int N) {     // out: [BT, N, 32]
    __shared__ float Wsh[FIN][FOUT];

    int n = blockIdx.x;
    int t = threadIdx.x;
    int bt = t >> 4;
    int f  = t & 15;

    // stage W (512 floats) into LDS
    Wsh[t >> 5][t & 31]       = W[t];
    Wsh[(t >> 5) + 8][t & 31] = W[t + 256];
    __syncthreads();

    const float* wbase = water + (size_t)bt * N * FIN + f;
    const float* gbase = gate  + (size_t)bt * N;

    int e0 = row_start[n], e1 = row_start[n + 1];
    float acc = 0.f;
    int e = e0;
    // unroll-by-4: batch the col loads, then the gathers -> 4x MLP
    for (; e + 4 <= e1; e += 4) {
        int c0 = col_s[e], c1 = col_s[e + 1], c2 = col_s[e + 2], c3 = col_s[e + 3];
        float v0 = val_s[e], v1 = val_s[e + 1], v2 = val_s[e + 2], v3 = val_s[e + 3];
        float g0 = gbase[c0], g1 = gbase[c1], g2 = gbase[c2], g3 = gbase[c3];
        float w0 = wbase[(size_t)c0 * FIN];
        float w1 = wbase[(size_t)c1 * FIN];
        float w2 = wbase[(size_t)c2 * FIN];
        float w3 = wbase[(size_t)c3 * FIN];
        acc += v0 * g0 * w0;
        acc += v1 * g1 * w1;
        acc += v2 * g2 * w2;
        acc += v3 * g3 * w3;
    }
    for (; e < e1; ++e) {
        int c = col_s[e];
        acc += val_s[e] * gbase[c] * wbase[(size_t)c * FIN];
    }

    // matmul: h[bt][k] lives in lane (bt*16+k) of this wave's 16-lane group
    float o0 = bvec[f], o1 = bvec[f + 16];
#pragma unroll
    for (int k = 0; k < FIN; ++k) {
        float hk = __shfl(acc, k, 16);
        o0 += hk * Wsh[k][f];
        o1 += hk * Wsh[k][f + 16];
    }

    // LayerNorm over 32 channels of (bt, n): 16 lanes x 2 values
    float s  = o0 + o1;
    float sq = o0 * o0 + o1 * o1;
#pragma unroll
    for (int off = 8; off >= 1; off >>= 1) {
        s  += __shfl_xor(s,  off, 16);
        sq += __shfl_xor(sq, off, 16);
    }
    float mu  = s * (1.f / 32.f);
    float var = sq * (1.f / 32.f) - mu * mu;
    float inv = rsqrtf(var + 1e-3f);
    o0 = (o0 - mu) * inv * gamma[f]      + beta[f];
    o1 = (o1 - mu) * inv * gamma[f + 16] + beta[f + 16];

    float* op = out + (size_t)bt * N * FOUT + (size_t)n * FOUT;
    op[f]      = o0;
    op[f + 16] = o1;
}

// ---------------- launch ----------------

extern "C" void kernel_launch(void* const* d_in, const int* in_sizes, int n_in,
                              void* d_out, int out_size, void* d_ws, size_t ws_size,
                              hipStream_t stream) {
    const float* water    = (const float*)d_in[0];
    const float* st       = (const float*)d_in[1];
    const int*   adj_rows = (const int*)  d_in[2];
    const int*   adj_cols = (const int*)  d_in[3];
    const float* adj_vals = (const float*)d_in[4];
    const float* W_feat   = (const float*)d_in[5];
    const float* b_feat   = (const float*)d_in[6];
    const float* Wg1      = (const float*)d_in[7];
    const float* bg1      = (const float*)d_in[8];
    const float* Wg2      = (const float*)d_in[9];
    const float* bg2      = (const float*)d_in[10];
    const float* ln_gamma = (const float*)d_in[11];
    const float* ln_beta  = (const float*)d_in[12];
    const float* min_gate = (const float*)d_in[13];
    float* out = (float*)d_out;

    int N = in_sizes[0] / (BT * FIN);
    int E = in_sizes[2];

    char* ws = (char*)d_ws;
    size_t off = 0;
    auto alloc = [&](size_t bytes) -> void* {
        off = (off + 255) & ~(size_t)255;
        void* p = ws + off;
        off += bytes;
        return p;
    };
    int*   counts    = (int*)  alloc((size_t)N * sizeof(int));
    int*   cursor    = (int*)  alloc((size_t)N * sizeof(int));   // contiguous with counts
    int*   row_start = (int*)  alloc((size_t)(N + 1) * sizeof(int));
    int*   col_s     = (int*)  alloc((size_t)E * sizeof(int));
    float* val_s     = (float*)alloc((size_t)E * sizeof(float));
    float* gate      = (float*)alloc((size_t)N * BT * sizeof(float));

    // counts & cursor are adjacent and both N*4B (N*4 is 256B-aligned) -> one memset
    hipMemsetAsync(counts, 0, (size_t)2 * N * sizeof(int), stream);

    int eb = (E + 255) / 256;
    hist_kernel<<<eb, 256, 0, stream>>>(adj_rows, counts, E);
    scan_kernel<<<1, 1024, 0, stream>>>(counts, row_start, N);
    scatter_kernel<<<eb, 256, 0, stream>>>(adj_rows, adj_cols, adj_vals,
                                           row_start, cursor, col_s, val_s, E);
    gate_kernel<<<(N * BT + 255) / 256, 256, 0, stream>>>(
        st, Wg1, bg1, Wg2, bg2, min_gate, gate, N * BT);
    spmm_ln_kernel<<<N, 256, 0, stream>>>(
        water, gate, row_start, col_s, val_s, W_feat, b_feat, ln_gamma, ln_beta, out, N);
}

// Round 3
// 216.933 us; speedup vs baseline: 2.1086x; 2.1086x over previous
//
#include <hip/hip_runtime.h>

#define BT   16
#define FIN  16
#define FOUT 32

// ---------------- CSR build ----------------

__global__ __launch_bounds__(256) void hist_kernel(const int* __restrict__ rows,
                                                   int* __restrict__ counts, int E) {
    int e = blockIdx.x * blockDim.x + threadIdx.x;
    if (e < E) atomicAdd(&counts[rows[e]], 1);
}

// 3-level scan over N=65536 counts: 256 blocks x 256 -> 256 partials -> add-back
__global__ __launch_bounds__(256) void scan1_kernel(const int* __restrict__ counts,
                                                    int* __restrict__ row_start,
                                                    int* __restrict__ bsum) {
    __shared__ int sh[256];
    int t = threadIdx.x;
    int i = blockIdx.x * 256 + t;
    int v = counts[i];
    sh[t] = v;
    __syncthreads();
    for (int off = 1; off < 256; off <<= 1) {
        int u = (t >= off) ? sh[t - off] : 0;
        __syncthreads();
        sh[t] += u;
        __syncthreads();
    }
    row_start[i] = sh[t] - v;                 // exclusive within block
    if (t == 255) bsum[blockIdx.x] = sh[255]; // block total
}

__global__ __launch_bounds__(256) void scan2_kernel(int* __restrict__ bsum,
                                                    int* __restrict__ boff,
                                                    int* __restrict__ row_start, int N) {
    __shared__ int sh[256];
    int t = threadIdx.x;
    int v = bsum[t];
    sh[t] = v;
    __syncthreads();
    for (int off = 1; off < 256; off <<= 1) {
        int u = (t >= off) ? sh[t - off] : 0;
        __syncthreads();
        sh[t] += u;
        __syncthreads();
    }
    boff[t] = sh[t] - v;                      // exclusive block offsets
    if (t == 255) row_start[N] = sh[255];     // grand total
}

__global__ __launch_bounds__(256) void scan3_kernel(int* __restrict__ row_start,
                                                    const int* __restrict__ boff) {
    int i = blockIdx.x * 256 + threadIdx.x;
    row_start[i] += boff[i >> 8];
}

__global__ __launch_bounds__(256) void scatter_kernel(const int* __restrict__ rows,
                                                      const int* __restrict__ cols,
                                                      const float* __restrict__ vals,
                                                      const int* __restrict__ row_start,
                                                      int* __restrict__ cursor,
                                                      int2* __restrict__ edge_s, int E) {
    int e = blockIdx.x * blockDim.x + threadIdx.x;
    if (e >= E) return;
    int r = rows[e];
    int pos = row_start[r] + atomicAdd(&cursor[r], 1);
    edge_s[pos] = make_int2(cols[e], __float_as_int(vals[e]));
}

// ---------------- gate + transpose:  x[n][bt*16+f] = water[bt][n][f] * gate(bt,n) ----------------

__global__ __launch_bounds__(256) void gate_x_kernel(
        const float* __restrict__ water,  // [BT, N, 16]
        const float* __restrict__ st,     // [BT, N, 8]
        const float* __restrict__ Wg1, const float* __restrict__ bg1,
        const float* __restrict__ Wg2, const float* __restrict__ bg2,
        const float* __restrict__ min_gate,
        float* __restrict__ x, int N) {
    int t = blockIdx.x * blockDim.x + threadIdx.x;
    if (t >= N * BT) return;
    int bt = t & (BT - 1);
    int n  = t >> 4;

    const float4* sp = (const float4*)(st + ((size_t)bt * N + n) * 8);
    float4 s0 = sp[0], s1 = sp[1];
    float g1 = s0.x * Wg1[0] + s0.y * Wg1[1] + s0.z * Wg1[2] + bg1[0];
    float g2 = s0.w * Wg2[0] + s1.x * Wg2[1] + s1.y * Wg2[2] + s1.z * Wg2[3] + s1.w * Wg2[4] + bg2[0];
    g1 = 1.f / (1.f + __expf(-g1));
    g2 = 1.f / (1.f + __expf(-g2));
    float gate = fmaxf(g1 * g2, min_gate[0]);

    const float4* wp = (const float4*)(water + ((size_t)bt * N + n) * FIN);
    float4*       xp = (float4*)(x + ((size_t)n * BT + bt) * FIN);
#pragma unroll
    for (int k = 0; k < 4; ++k) {
        float4 w = wp[k];
        w.x *= gate; w.y *= gate; w.z *= gate; w.w *= gate;
        xp[k] = w;
    }
}

// ---------------- fused SpMM + 16->32 matmul + LayerNorm ----------------
// One wave (64 lanes) per node; lane l gathers float4 = x[c][l*4 .. l*4+3]
// -> lane holds h for (bt = l>>2, f = (l&3)*4 .. +3).

__global__ __launch_bounds__(256) void spmm_ln_kernel(
        const float* __restrict__ x,          // [N, 256]
        const int* __restrict__ row_start,    // [N+1]
        const int2* __restrict__ edge_s,      // [E] {col, val}
        const float* __restrict__ W,          // [16, 32]
        const float* __restrict__ bvec,
        const float* __restrict__ gamma,
        const float* __restrict__ beta,
        float* __restrict__ out, int N) {     // out: [BT, N, 32]
    __shared__ float Wsh[FIN][FOUT];
    __shared__ float psh[3][FOUT];            // bias, gamma, beta

    int t = threadIdx.x;
    Wsh[t >> 5][t & 31]       = W[t];
    Wsh[(t >> 5) + 8][t & 31] = W[t + 256];
    if (t < 32)       psh[0][t]      = bvec[t];
    else if (t < 64)  psh[1][t - 32] = gamma[t - 32];
    else if (t < 96)  psh[2][t - 64] = beta[t - 64];
    __syncthreads();

    int wave = t >> 6;
    int l    = t & 63;
    int n    = blockIdx.x * 4 + wave;

    int e0 = row_start[n], e1 = row_start[n + 1];
    const float4* xv = (const float4*)x;      // node c -> xv[c*64 + l]

    float4 acc = {0.f, 0.f, 0.f, 0.f};
    int e = e0;
    for (; e + 4 <= e1; e += 4) {
        int2 d0 = edge_s[e], d1 = edge_s[e + 1], d2 = edge_s[e + 2], d3 = edge_s[e + 3];
        float4 g0 = xv[(size_t)d0.x * 64 + l];
        float4 g1 = xv[(size_t)d1.x * 64 + l];
        float4 g2 = xv[(size_t)d2.x * 64 + l];
        float4 g3 = xv[(size_t)d3.x * 64 + l];
        float v0 = __int_as_float(d0.y), v1 = __int_as_float(d1.y);
        float v2 = __int_as_float(d2.y), v3 = __int_as_float(d3.y);
        acc.x += v0 * g0.x; acc.y += v0 * g0.y; acc.z += v0 * g0.z; acc.w += v0 * g0.w;
        acc.x += v1 * g1.x; acc.y += v1 * g1.y; acc.z += v1 * g1.z; acc.w += v1 * g1.w;
        acc.x += v2 * g2.x; acc.y += v2 * g2.y; acc.z += v2 * g2.z; acc.w += v2 * g2.w;
        acc.x += v3 * g3.x; acc.y += v3 * g3.y; acc.z += v3 * g3.z; acc.w += v3 * g3.w;
    }
    for (; e < e1; ++e) {
        int2 d0 = edge_s[e];
        float4 g0 = xv[(size_t)d0.x * 64 + l];
        float v0 = __int_as_float(d0.y);
        acc.x += v0 * g0.x; acc.y += v0 * g0.y; acc.z += v0 * g0.z; acc.w += v0 * g0.w;
    }

    // matmul: lane (bt, d=l&3) computes out channels j = d*8 .. d*8+7
    int d = l & 3;
    float o[8];
#pragma unroll
    for (int jj = 0; jj < 8; ++jj) o[jj] = psh[0][d * 8 + jj];
#pragma unroll
    for (int q = 0; q < 4; ++q) {
        float hq[4];
        hq[0] = __shfl(acc.x, q, 4);
        hq[1] = __shfl(acc.y, q, 4);
        hq[2] = __shfl(acc.z, q, 4);
        hq[3] = __shfl(acc.w, q, 4);
#pragma unroll
        for (int m = 0; m < 4; ++m) {
            float hk = hq[m];
#pragma unroll
            for (int jj = 0; jj < 8; ++jj)
                o[jj] += hk * Wsh[q * 4 + m][d * 8 + jj];
        }
    }

    // LayerNorm over 32 channels: 4 lanes x 8 values
    float s = 0.f, sq = 0.f;
#pragma unroll
    for (int jj = 0; jj < 8; ++jj) { s += o[jj]; sq += o[jj] * o[jj]; }
    s  += __shfl_xor(s,  1, 4);  sq += __shfl_xor(sq, 1, 4);
    s  += __shfl_xor(s,  2, 4);  sq += __shfl_xor(sq, 2, 4);
    float mu  = s * (1.f / 32.f);
    float var = sq * (1.f / 32.f) - mu * mu;
    float inv = rsqrtf(var + 1e-3f);

    float4 r0, r1;
    float* rp = (float*)&r0;
#pragma unroll
    for (int jj = 0; jj < 8; ++jj) {
        float val = (o[jj] - mu) * inv * psh[1][d * 8 + jj] + psh[2][d * 8 + jj];
        if (jj < 4) ((float*)&r0)[jj] = val;
        else        ((float*)&r1)[jj - 4] = val;
    }
    (void)rp;
    int bt = l >> 2;
    float4* op = (float4*)(out + (size_t)bt * N * FOUT + (size_t)n * FOUT + d * 8);
    op[0] = r0;
    op[1] = r1;
}

// ---------------- launch ----------------

extern "C" void kernel_launch(void* const* d_in, const int* in_sizes, int n_in,
                              void* d_out, int out_size, void* d_ws, size_t ws_size,
                              hipStream_t stream) {
    const float* water    = (const float*)d_in[0];
    const float* st       = (const float*)d_in[1];
    const int*   adj_rows = (const int*)  d_in[2];
    const int*   adj_cols = (const int*)  d_in[3];
    const float* adj_vals = (const float*)d_in[4];
    const float* W_feat   = (const float*)d_in[5];
    const float* b_feat   = (const float*)d_in[6];
    const float* Wg1      = (const float*)d_in[7];
    const float* bg1      = (const float*)d_in[8];
    const float* Wg2      = (const float*)d_in[9];
    const float* bg2      = (const float*)d_in[10];
    const float* ln_gamma = (const float*)d_in[11];
    const float* ln_beta  = (const float*)d_in[12];
    const float* min_gate = (const float*)d_in[13];
    float* out = (float*)d_out;

    int N = in_sizes[0] / (BT * FIN);
    int E = in_sizes[2];

    char* ws = (char*)d_ws;
    size_t off = 0;
    auto alloc = [&](size_t bytes) -> void* {
        off = (off + 255) & ~(size_t)255;
        void* p = ws + off;
        off += bytes;
        return p;
    };
    int*   counts    = (int*)  alloc((size_t)N * sizeof(int));
    int*   cursor    = (int*)  alloc((size_t)N * sizeof(int));   // contiguous with counts
    int*   row_start = (int*)  alloc((size_t)(N + 1) * sizeof(int));
    int*   bsum      = (int*)  alloc(256 * sizeof(int));
    int*   boff      = (int*)  alloc(256 * sizeof(int));
    int2*  edge_s    = (int2*) alloc((size_t)E * sizeof(int2));
    float* x         = (float*)alloc((size_t)N * BT * FIN * sizeof(float));

    hipMemsetAsync(counts, 0, (size_t)2 * N * sizeof(int), stream);

    int eb = (E + 255) / 256;
    int nb = N / 256;  // 256
    hist_kernel<<<eb, 256, 0, stream>>>(adj_rows, counts, E);
    scan1_kernel<<<nb, 256, 0, stream>>>(counts, row_start, bsum);
    scan2_kernel<<<1, 256, 0, stream>>>(bsum, boff, row_start, N);
    scan3_kernel<<<nb, 256, 0, stream>>>(row_start, boff);
    scatter_kernel<<<eb, 256, 0, stream>>>(adj_rows, adj_cols, adj_vals,
                                           row_start, cursor, edge_s, E);
    gate_x_kernel<<<(N * BT + 255) / 256, 256, 0, stream>>>(
        water, st, Wg1, bg1, Wg2, bg2, min_gate, x, N);
    spmm_ln_kernel<<<N / 4, 256, 0, stream>>>(
        x, row_start, edge_s, W_feat, b_feat, ln_gamma, ln_beta, out, N);
}